// Round 12
// baseline (235.463 us; speedup 1.0000x reference)
//
#include <hip/hip_runtime.h>
#include <math.h>

#define BB 32
#define LL 4096
#define DD 1024
#define NCH 16     // l-chunks; with NJT=64 -> 1024 blocks (4/CU, proven safe)
#define NJT 64     // j-tiles of 64 columns
#define CTILE 256  // l-rows staged in LDS at once (32 KB)

typedef float f4 __attribute__((ext_vector_type(4)));

// Kernel 1: dlT[l*BB + b] = dot(doc[b,l,:], W[l,:]) + bias[l]
// Frozen r9 structure + per-call zeroing of the NJT finish-counters (block 0).
__global__ __launch_bounds__(256, 8) void k_dot(const float* __restrict__ doc,
                                                const float* __restrict__ W,
                                                const float* __restrict__ bias,
                                                float* __restrict__ dlT,
                                                int* __restrict__ cnt) {
  if (blockIdx.x == 0 && threadIdx.x < NJT) cnt[threadIdx.x] = 0;

  const int bid  = (blockIdx.x & 7) * 2048 + (blockIdx.x >> 3);  // bijective: 16384 % 8 == 0
  const int wid  = (bid * 256 + (int)threadIdx.x) >> 6;  // pair id [0, 65536)
  const int lane = threadIdx.x & 63;
  const int b  = wid & 31;
  const int l  = (wid >> 5) << 1;

  const f4* dp = reinterpret_cast<const f4*>(doc) +
                 (((size_t)b << 20) + ((size_t)l << 8));
  const f4* wp = reinterpret_cast<const f4*>(W) + ((size_t)l << 8);

  float acc0 = 0.f, acc1 = 0.f;
  {
    f4 a0 = __builtin_nontemporal_load(&dp[lane]);
    f4 a1 = __builtin_nontemporal_load(&dp[lane + 64]);
    f4 a2 = __builtin_nontemporal_load(&dp[lane + 128]);
    f4 a3 = __builtin_nontemporal_load(&dp[lane + 192]);
    f4 w0 = wp[lane];
    f4 w1 = wp[lane + 64];
    f4 w2 = wp[lane + 128];
    f4 w3 = wp[lane + 192];
    acc0 = fmaf(a0.x, w0.x, acc0); acc0 = fmaf(a0.y, w0.y, acc0);
    acc0 = fmaf(a0.z, w0.z, acc0); acc0 = fmaf(a0.w, w0.w, acc0);
    acc0 = fmaf(a1.x, w1.x, acc0); acc0 = fmaf(a1.y, w1.y, acc0);
    acc0 = fmaf(a1.z, w1.z, acc0); acc0 = fmaf(a1.w, w1.w, acc0);
    acc0 = fmaf(a2.x, w2.x, acc0); acc0 = fmaf(a2.y, w2.y, acc0);
    acc0 = fmaf(a2.z, w2.z, acc0); acc0 = fmaf(a2.w, w2.w, acc0);
    acc0 = fmaf(a3.x, w3.x, acc0); acc0 = fmaf(a3.y, w3.y, acc0);
    acc0 = fmaf(a3.z, w3.z, acc0); acc0 = fmaf(a3.w, w3.w, acc0);
  }
  {
    f4 a0 = __builtin_nontemporal_load(&dp[lane + 256]);
    f4 a1 = __builtin_nontemporal_load(&dp[lane + 320]);
    f4 a2 = __builtin_nontemporal_load(&dp[lane + 384]);
    f4 a3 = __builtin_nontemporal_load(&dp[lane + 448]);
    f4 w0 = wp[lane + 256];
    f4 w1 = wp[lane + 320];
    f4 w2 = wp[lane + 384];
    f4 w3 = wp[lane + 448];
    acc1 = fmaf(a0.x, w0.x, acc1); acc1 = fmaf(a0.y, w0.y, acc1);
    acc1 = fmaf(a0.z, w0.z, acc1); acc1 = fmaf(a0.w, w0.w, acc1);
    acc1 = fmaf(a1.x, w1.x, acc1); acc1 = fmaf(a1.y, w1.y, acc1);
    acc1 = fmaf(a1.z, w1.z, acc1); acc1 = fmaf(a1.w, w1.w, acc1);
    acc1 = fmaf(a2.x, w2.x, acc1); acc1 = fmaf(a2.y, w2.y, acc1);
    acc1 = fmaf(a2.z, w2.z, acc1); acc1 = fmaf(a2.w, w2.w, acc1);
    acc1 = fmaf(a3.x, w3.x, acc1); acc1 = fmaf(a3.y, w3.y, acc1);
    acc1 = fmaf(a3.z, w3.z, acc1); acc1 = fmaf(a3.w, w3.w, acc1);
  }

  acc0 += __shfl_xor(acc0, 32);
  acc1 += __shfl_xor(acc1, 32);
  float c = (lane < 32) ? acc0 : acc1;
#pragma unroll
  for (int off = 16; off > 0; off >>= 1) c += __shfl_xor(c, off);

  if ((lane & 31) == 0) {
    const int row = l + (lane >> 5);
    dlT[(row << 5) + b] = c + bias[row];
  }
}

// Kernel 2 (fused): partials + last-block-per-j-tile applies sum+sigmoid.
// Classic threadfence-reduction pattern: each block stores its partials,
// fences, increments cnt[jt]; the block that observes old==nchunks-1 re-reads
// the (L2/L3-resident) partials for its 64 columns and writes final out.
// Output is independent of which block wins -> deterministic.
__global__ __launch_bounds__(256, 4) void k_gemm(const float* __restrict__ dlT,
                                                 const float* __restrict__ G,
                                                 float* __restrict__ part,
                                                 float* __restrict__ out,
                                                 int* __restrict__ cnt,
                                                 int chunk_l, int nchunks) {
  __shared__ float sdl[CTILE * BB];       // 32 KB
  const int jt   = blockIdx.x % NJT;      // j-tile (64 cols)
  const int s    = blockIdx.x / NJT;      // l-chunk
  const int lane = threadIdx.x & 63;
  const int w    = threadIdx.x >> 6;
  const int b0   = w << 3;                // this wave's b-octet
  const int j0   = (jt << 6) + lane;      // this thread's column
  const int l0   = s * chunk_l;

  float acc[8];
#pragma unroll
  for (int b = 0; b < 8; ++b) acc[b] = 0.f;

  for (int t0 = 0; t0 < chunk_l; t0 += CTILE) {
    __syncthreads();
    {
      const float4* src = reinterpret_cast<const float4*>(dlT + (size_t)(l0 + t0) * BB);
      float4* dst = reinterpret_cast<float4*>(sdl);
#pragma unroll
      for (int k = 0; k < (CTILE * BB / 4) / 256; ++k)
        dst[k * 256 + threadIdx.x] = src[k * 256 + threadIdx.x];
    }
    __syncthreads();

    const float* gb = G + (size_t)(l0 + t0) * LL + j0;
#pragma unroll 8
    for (int il = 0; il < CTILE; ++il) {
      const float g = gb[(size_t)il * LL];
      const float4 d01 = *reinterpret_cast<const float4*>(sdl + il * BB + b0);
      const float4 d23 = *reinterpret_cast<const float4*>(sdl + il * BB + b0 + 4);
      acc[0] = fmaf(d01.x, g, acc[0]);
      acc[1] = fmaf(d01.y, g, acc[1]);
      acc[2] = fmaf(d01.z, g, acc[2]);
      acc[3] = fmaf(d01.w, g, acc[3]);
      acc[4] = fmaf(d23.x, g, acc[4]);
      acc[5] = fmaf(d23.y, g, acc[5]);
      acc[6] = fmaf(d23.z, g, acc[6]);
      acc[7] = fmaf(d23.w, g, acc[7]);
    }
  }

  {
    float* po = part + (size_t)s * (BB * LL) + j0;
#pragma unroll
    for (int b = 0; b < 8; ++b) po[(size_t)(b0 + b) * LL] = acc[b];
  }

  // ---- finish protocol ----
  __threadfence();              // release: make this thread's partials visible
  __syncthreads();              // all threads of the block have fenced
  __shared__ int lastFlag;
  if (threadIdx.x == 0)
    lastFlag = (atomicAdd(&cnt[jt], 1) == nchunks - 1);
  __syncthreads();
  if (lastFlag) {
    __threadfence();            // acquire: see all blocks' partials
#pragma unroll
    for (int b = 0; b < 8; ++b) {
      const size_t off = (size_t)(b0 + b) * LL + j0;
      float ssum = 0.f;
      for (int c = 0; c < nchunks; ++c)
        ssum += part[(size_t)c * (BB * LL) + off];
      out[off] = 1.f / (1.f + expf(-ssum));
    }
  }
}

extern "C" void kernel_launch(void* const* d_in, const int* in_sizes, int n_in,
                              void* d_out, int out_size, void* d_ws, size_t ws_size,
                              hipStream_t stream) {
  const float* doc  = (const float*)d_in[0];  // [B, L, D]
  const float* W    = (const float*)d_in[1];  // [L, D]
  const float* bias = (const float*)d_in[2];  // [L]
  const float* G    = (const float*)d_in[3];  // [L, L]
  float* out = (float*)d_out;                 // [B, L]

  float* dlT = (float*)d_ws;                              // BB*LL floats = 512 KB
  const size_t dl_bytes  = (size_t)BB * LL * sizeof(float);
  const size_t per_chunk = (size_t)BB * LL * sizeof(float);
  float* part = (float*)((char*)d_ws + dl_bytes);

  int nchunks = NCH;
  size_t need_cnt = NJT * sizeof(int);
  size_t avail = ws_size > dl_bytes + need_cnt ? (ws_size - dl_bytes - need_cnt) / per_chunk : 0;
  if ((size_t)nchunks > avail) {
    nchunks = 1;
    while ((size_t)(nchunks * 2) <= avail && nchunks * 2 <= NCH) nchunks *= 2;
  }
  const int chunk_l = LL / nchunks;   // multiple of CTILE for nchunks <= 16
  int* cnt = (int*)((char*)d_ws + dl_bytes + (size_t)nchunks * per_chunk);

  k_dot<<<dim3((BB * LL / 2) / 4), dim3(256), 0, stream>>>(doc, W, bias, dlT, cnt);
  k_gemm<<<dim3(NJT * nchunks), dim3(256), 0, stream>>>(dlT, G, part, out, cnt,
                                                        chunk_l, nchunks);
}

// Round 13
// 111.739 us; speedup vs baseline: 2.1073x; 2.1073x over previous
//
#include <hip/hip_runtime.h>
#include <math.h>

#define BB 32
#define LL 4096
#define DD 1024
#define NCH 16   // l-chunks; with NJT=64 -> 1024 blocks (4/CU, proven safe)
#define NJT 64   // j-tiles of 64 columns
#define CTILE 256  // l-rows staged in LDS at once (32 KB)

typedef float f4 __attribute__((ext_vector_type(4)));

// Kernel 1: dlT[l*BB + b] = dot(doc[b,l,:], W[l,:]) + bias[l]
// Frozen r9 structure (wave per row-pair, NT doc loads, XCD-chunked swizzle,
// launch_bounds(256,8), folded 7-op reduce).
__global__ __launch_bounds__(256, 8) void k_dot(const float* __restrict__ doc,
                                                const float* __restrict__ W,
                                                const float* __restrict__ bias,
                                                float* __restrict__ dlT) {
  const int bid  = (blockIdx.x & 7) * 2048 + (blockIdx.x >> 3);  // bijective: 16384 % 8 == 0
  const int wid  = (bid * 256 + (int)threadIdx.x) >> 6;  // pair id [0, 65536)
  const int lane = threadIdx.x & 63;
  const int b  = wid & 31;
  const int l  = (wid >> 5) << 1;

  const f4* dp = reinterpret_cast<const f4*>(doc) +
                 (((size_t)b << 20) + ((size_t)l << 8));
  const f4* wp = reinterpret_cast<const f4*>(W) + ((size_t)l << 8);

  float acc0 = 0.f, acc1 = 0.f;
  {
    f4 a0 = __builtin_nontemporal_load(&dp[lane]);
    f4 a1 = __builtin_nontemporal_load(&dp[lane + 64]);
    f4 a2 = __builtin_nontemporal_load(&dp[lane + 128]);
    f4 a3 = __builtin_nontemporal_load(&dp[lane + 192]);
    f4 w0 = wp[lane];
    f4 w1 = wp[lane + 64];
    f4 w2 = wp[lane + 128];
    f4 w3 = wp[lane + 192];
    acc0 = fmaf(a0.x, w0.x, acc0); acc0 = fmaf(a0.y, w0.y, acc0);
    acc0 = fmaf(a0.z, w0.z, acc0); acc0 = fmaf(a0.w, w0.w, acc0);
    acc0 = fmaf(a1.x, w1.x, acc0); acc0 = fmaf(a1.y, w1.y, acc0);
    acc0 = fmaf(a1.z, w1.z, acc0); acc0 = fmaf(a1.w, w1.w, acc0);
    acc0 = fmaf(a2.x, w2.x, acc0); acc0 = fmaf(a2.y, w2.y, acc0);
    acc0 = fmaf(a2.z, w2.z, acc0); acc0 = fmaf(a2.w, w2.w, acc0);
    acc0 = fmaf(a3.x, w3.x, acc0); acc0 = fmaf(a3.y, w3.y, acc0);
    acc0 = fmaf(a3.z, w3.z, acc0); acc0 = fmaf(a3.w, w3.w, acc0);
  }
  {
    f4 a0 = __builtin_nontemporal_load(&dp[lane + 256]);
    f4 a1 = __builtin_nontemporal_load(&dp[lane + 320]);
    f4 a2 = __builtin_nontemporal_load(&dp[lane + 384]);
    f4 a3 = __builtin_nontemporal_load(&dp[lane + 448]);
    f4 w0 = wp[lane + 256];
    f4 w1 = wp[lane + 320];
    f4 w2 = wp[lane + 384];
    f4 w3 = wp[lane + 448];
    acc1 = fmaf(a0.x, w0.x, acc1); acc1 = fmaf(a0.y, w0.y, acc1);
    acc1 = fmaf(a0.z, w0.z, acc1); acc1 = fmaf(a0.w, w0.w, acc1);
    acc1 = fmaf(a1.x, w1.x, acc1); acc1 = fmaf(a1.y, w1.y, acc1);
    acc1 = fmaf(a1.z, w1.z, acc1); acc1 = fmaf(a1.w, w1.w, acc1);
    acc1 = fmaf(a2.x, w2.x, acc1); acc1 = fmaf(a2.y, w2.y, acc1);
    acc1 = fmaf(a2.z, w2.z, acc1); acc1 = fmaf(a2.w, w2.w, acc1);
    acc1 = fmaf(a3.x, w3.x, acc1); acc1 = fmaf(a3.y, w3.y, acc1);
    acc1 = fmaf(a3.z, w3.z, acc1); acc1 = fmaf(a3.w, w3.w, acc1);
  }

  acc0 += __shfl_xor(acc0, 32);
  acc1 += __shfl_xor(acc1, 32);
  float c = (lane < 32) ? acc0 : acc1;
#pragma unroll
  for (int off = 16; off > 0; off >>= 1) c += __shfl_xor(c, off);

  if ((lane & 31) == 0) {
    const int row = l + (lane >> 5);
    dlT[(row << 5) + b] = c + bias[row];
  }
}

// Kernel 2: part[s][b*LL + j] = sum_{l in chunk s} dlT[l*BB+b] * G[l*LL+j]
// 64 j-tiles x 64 cols, nchunks=16 -> 1024 blocks (4/CU). Whole 256-row
// dlT tile (32 KB) staged in LDS ONCE; inner loop barrier-free.
__global__ __launch_bounds__(256, 4) void k_gemm(const float* __restrict__ dlT,
                                                 const float* __restrict__ G,
                                                 float* __restrict__ part,
                                                 int chunk_l) {
  __shared__ float sdl[CTILE * BB];       // 32 KB
  const int jt   = blockIdx.x % NJT;      // j-tile (64 cols)
  const int s    = blockIdx.x / NJT;      // l-chunk
  const int lane = threadIdx.x & 63;
  const int w    = threadIdx.x >> 6;
  const int b0   = w << 3;                // this wave's b-octet
  const int j0   = (jt << 6) + lane;      // this thread's column
  const int l0   = s * chunk_l;

  float acc[8];
#pragma unroll
  for (int b = 0; b < 8; ++b) acc[b] = 0.f;

  for (int t0 = 0; t0 < chunk_l; t0 += CTILE) {
    __syncthreads();                      // safe re-stage (no-op cost on tile 0)
    {
      const float4* src = reinterpret_cast<const float4*>(dlT + (size_t)(l0 + t0) * BB);
      float4* dst = reinterpret_cast<float4*>(sdl);
#pragma unroll
      for (int k = 0; k < (CTILE * BB / 4) / 256; ++k)
        dst[k * 256 + threadIdx.x] = src[k * 256 + threadIdx.x];
    }
    __syncthreads();

    const float* gb = G + (size_t)(l0 + t0) * LL + j0;
#pragma unroll 8
    for (int il = 0; il < CTILE; ++il) {
      const float g = gb[(size_t)il * LL];
      const float4 d01 = *reinterpret_cast<const float4*>(sdl + il * BB + b0);
      const float4 d23 = *reinterpret_cast<const float4*>(sdl + il * BB + b0 + 4);
      acc[0] = fmaf(d01.x, g, acc[0]);
      acc[1] = fmaf(d01.y, g, acc[1]);
      acc[2] = fmaf(d01.z, g, acc[2]);
      acc[3] = fmaf(d01.w, g, acc[3]);
      acc[4] = fmaf(d23.x, g, acc[4]);
      acc[5] = fmaf(d23.y, g, acc[5]);
      acc[6] = fmaf(d23.z, g, acc[6]);
      acc[7] = fmaf(d23.w, g, acc[7]);
    }
  }

  float* po = part + (size_t)s * (BB * LL) + j0;
#pragma unroll
  for (int b = 0; b < 8; ++b) po[(size_t)(b0 + b) * LL] = acc[b];
}

// Kernel 3: out[i4] = sigmoid(sum_s part[s][i4]) — float4 vectorized.
__global__ __launch_bounds__(256) void k_reduce(const float* __restrict__ part,
                                                float* __restrict__ out,
                                                int nchunks) {
  const int i4 = blockIdx.x * 256 + threadIdx.x;  // float4 index [0, BB*LL/4)
  f4 s = {0.f, 0.f, 0.f, 0.f};
  for (int c = 0; c < nchunks; ++c)
    s += *reinterpret_cast<const f4*>(part + (size_t)c * (BB * LL) + ((size_t)i4 << 2));
  f4 r;
  r.x = 1.f / (1.f + expf(-s.x));
  r.y = 1.f / (1.f + expf(-s.y));
  r.z = 1.f / (1.f + expf(-s.z));
  r.w = 1.f / (1.f + expf(-s.w));
  *reinterpret_cast<f4*>(out + ((size_t)i4 << 2)) = r;
}

extern "C" void kernel_launch(void* const* d_in, const int* in_sizes, int n_in,
                              void* d_out, int out_size, void* d_ws, size_t ws_size,
                              hipStream_t stream) {
  const float* doc  = (const float*)d_in[0];  // [B, L, D]
  const float* W    = (const float*)d_in[1];  // [L, D]
  const float* bias = (const float*)d_in[2];  // [L]
  const float* G    = (const float*)d_in[3];  // [L, L]
  float* out = (float*)d_out;                 // [B, L]

  float* dlT = (float*)d_ws;                              // BB*LL floats = 512 KB
  const size_t dl_bytes  = (size_t)BB * LL * sizeof(float);
  const size_t per_chunk = (size_t)BB * LL * sizeof(float);
  float* part = (float*)((char*)d_ws + dl_bytes);

  // l-split: NCH=16 chunks (with NJT=64 tiles -> 1024 blocks, 4/CU).
  int nchunks = NCH;
  size_t avail = ws_size > dl_bytes ? (ws_size - dl_bytes) / per_chunk : 0;
  if ((size_t)nchunks > avail) {
    nchunks = 1;
    while ((size_t)(nchunks * 2) <= avail && nchunks * 2 <= NCH) nchunks *= 2;
  }
  const int chunk_l = LL / nchunks;   // multiple of CTILE for nchunks <= 16

  k_dot<<<dim3((BB * LL / 2) / 4), dim3(256), 0, stream>>>(doc, W, bias, dlT);
  k_gemm<<<dim3(NJT * nchunks), dim3(256), 0, stream>>>(dlT, G, part, chunk_l);
  k_reduce<<<dim3((BB * LL / 4) / 256), dim3(256), 0, stream>>>(part, out, nchunks);
}